// Round 1
// baseline (10829.256 us; speedup 1.0000x reference)
//
#include <hip/hip_runtime.h>
#include <math.h>

#define NT 4096      // B*T tokens
#define DD 512
#define TT 2048
#define HH 8
#define DH 64
#define FFD 2048
#define NSLOT 32768
#define STILE 2048
#define TOPK 8

__device__ __forceinline__ float gelu_f(float x) {
  float x3 = x * x * x;
  return 0.5f * x * (1.0f + tanhf(0.7978845608028654f * (x + 0.044715f * x3)));
}

// ---------------- embed: x = tok[ids] + pos ----------------
__global__ __launch_bounds__(128) void embed_k(const int* __restrict__ ids,
                                               const float* __restrict__ tok,
                                               const float* __restrict__ pos,
                                               float* __restrict__ x) {
  int n = blockIdx.x;
  int t = threadIdx.x;           // 128 threads * 4 floats = 512
  int id = ids[n];
  int tp = n & (TT - 1);
  const float4 a = *(const float4*)(tok + (size_t)id * DD + t * 4);
  const float4 b = *(const float4*)(pos + (size_t)tp * DD + t * 4);
  float4 r;
  r.x = a.x + b.x; r.y = a.y + b.y; r.z = a.z + b.z; r.w = a.w + b.w;
  *(float4*)(x + (size_t)n * DD + t * 4) = r;
}

// ---------------- RMS norm, in place ----------------
__global__ __launch_bounds__(128) void rms_k(float* __restrict__ x, const float* __restrict__ w) {
  int n = blockIdx.x;
  int t = threadIdx.x;           // 128 threads * 4 floats
  float4 v = *(float4*)(x + (size_t)n * DD + t * 4);
  float ss = v.x * v.x + v.y * v.y + v.z * v.z + v.w * v.w;
#pragma unroll
  for (int off = 32; off > 0; off >>= 1) ss += __shfl_xor(ss, off);
  __shared__ float part[2];
  if ((t & 63) == 0) part[t >> 6] = ss;
  __syncthreads();
  float scale = rsqrtf((part[0] + part[1]) * (1.0f / DD) + 1e-8f);
  const float4 wv = *(const float4*)(w + t * 4);
  v.x *= scale * wv.x; v.y *= scale * wv.y; v.z *= scale * wv.z; v.w *= scale * wv.w;
  *(float4*)(x + (size_t)n * DD + t * 4) = v;
}

// ---------------- generic fp32 GEMM ----------------
// C[N,M] = act( (A[N,K] @ B) * alpha + bias[M] + R[N,M] )
// transB==0: B is [K,M] row-major. transB==1: B is [M,K] row-major (dot of rows).
// N%128==0, M%128==0, K%16==0 assumed.
#define GBM 128
#define GBN 128
#define GBK 16

__global__ __launch_bounds__(256) void gemm_k(
    const float* __restrict__ A, const float* __restrict__ B,
    const float* __restrict__ bias, const float* __restrict__ R,
    float* __restrict__ C, int N, int M, int K,
    float alpha, int act, int transB)
{
  __shared__ float As[GBK][GBM + 4];   // [k][m]
  __shared__ float Bs[GBK][GBN + 4];   // [k][n]
  const int tid = threadIdx.x;
  const int tx = tid & 15;
  const int ty = tid >> 4;
  const int bn = blockIdx.x * GBN;
  const int bm = blockIdx.y * GBM;
  float acc[8][8];
#pragma unroll
  for (int i = 0; i < 8; ++i)
#pragma unroll
    for (int j = 0; j < 8; ++j) acc[i][j] = 0.0f;

  for (int k0 = 0; k0 < K; k0 += GBK) {
    // A tile: rows bm..bm+127, k0..k0+15 → transposed store
#pragma unroll
    for (int i = tid; i < GBM * GBK / 4; i += 256) {
      int r = i >> 2, c4 = i & 3;
      const float4 av = *(const float4*)(A + (size_t)(bm + r) * K + (k0 + c4 * 4));
      As[c4 * 4 + 0][r] = av.x; As[c4 * 4 + 1][r] = av.y;
      As[c4 * 4 + 2][r] = av.z; As[c4 * 4 + 3][r] = av.w;
    }
    if (transB) {
#pragma unroll
      for (int i = tid; i < GBN * GBK / 4; i += 256) {
        int r = i >> 2, c4 = i & 3;
        const float4 bv = *(const float4*)(B + (size_t)(bn + r) * K + (k0 + c4 * 4));
        Bs[c4 * 4 + 0][r] = bv.x; Bs[c4 * 4 + 1][r] = bv.y;
        Bs[c4 * 4 + 2][r] = bv.z; Bs[c4 * 4 + 3][r] = bv.w;
      }
    } else {
#pragma unroll
      for (int i = tid; i < GBK * GBN / 4; i += 256) {
        int r = i >> 5, c4 = i & 31;
        const float4 bv = *(const float4*)(B + (size_t)(k0 + r) * M + (bn + c4 * 4));
        *(float4*)&Bs[r][c4 * 4] = bv;
      }
    }
    __syncthreads();
#pragma unroll
    for (int kk = 0; kk < GBK; ++kk) {
      const float4 a0 = *(const float4*)&As[kk][ty * 8];
      const float4 a1 = *(const float4*)&As[kk][ty * 8 + 4];
      const float4 b0 = *(const float4*)&Bs[kk][tx * 8];
      const float4 b1 = *(const float4*)&Bs[kk][tx * 8 + 4];
      const float av[8] = {a0.x, a0.y, a0.z, a0.w, a1.x, a1.y, a1.z, a1.w};
      const float bv[8] = {b0.x, b0.y, b0.z, b0.w, b1.x, b1.y, b1.z, b1.w};
#pragma unroll
      for (int ii = 0; ii < 8; ++ii)
#pragma unroll
        for (int jj = 0; jj < 8; ++jj)
          acc[ii][jj] = fmaf(av[ii], bv[jj], acc[ii][jj]);
    }
    __syncthreads();
  }
  // epilogue
#pragma unroll
  for (int ii = 0; ii < 8; ++ii) {
    const int row = bm + ty * 8 + ii;
    float o[8];
#pragma unroll
    for (int jj = 0; jj < 8; ++jj) {
      const int col = bn + tx * 8 + jj;
      float v = acc[ii][jj] * alpha;
      if (bias) v += bias[col];
      if (R) v += R[(size_t)row * M + col];
      if (act == 1) v = gelu_f(v);
      o[jj] = v;
    }
    *(float4*)(C + (size_t)row * M + bn + tx * 8)     = *(float4*)&o[0];
    *(float4*)(C + (size_t)row * M + bn + tx * 8 + 4) = *(float4*)&o[4];
  }
}

// ---------------- flash attention (fp32), head dim 64, no mask ----------------
// grid: (T/64, H, B), block: 64 threads. Each block: 64 q-rows, one head.
__global__ __launch_bounds__(64) void attn_k(const float* __restrict__ Q,
                                             const float* __restrict__ K,
                                             const float* __restrict__ V,
                                             float* __restrict__ O) {
  __shared__ float Qst[DH][68];   // [d][q]
  __shared__ float KP[DH][68];    // phase 1: K as [d][k]; phase 2: P as [k][q]
  __shared__ float Vs[64][68];    // [k][d]
  const int tid = threadIdx.x;
  const int tx = tid & 7;         // k-cols / d-cols group (8 wide)
  const int ty = tid >> 3;        // q-rows group (8 wide)
  const int qt = blockIdx.x, h = blockIdx.y, b = blockIdx.z;
  const int n0 = b * TT + qt * 64;
  const int h0 = h * DH;

  // load Q tile transposed: [64 q][64 d] → Qst[d][q]
#pragma unroll
  for (int i = tid; i < 64 * 16; i += 64) {
    int r = i >> 4, c4 = i & 15;
    const float4 qv = *(const float4*)(Q + (size_t)(n0 + r) * DD + h0 + c4 * 4);
    Qst[c4 * 4 + 0][r] = qv.x; Qst[c4 * 4 + 1][r] = qv.y;
    Qst[c4 * 4 + 2][r] = qv.z; Qst[c4 * 4 + 3][r] = qv.w;
  }
  float m[8], l[8], acc[8][8];
#pragma unroll
  for (int i = 0; i < 8; ++i) {
    m[i] = -INFINITY; l[i] = 0.0f;
#pragma unroll
    for (int j = 0; j < 8; ++j) acc[i][j] = 0.0f;
  }

  for (int kt = 0; kt < TT / 64; ++kt) {
    __syncthreads();   // previous PV reads of KP/Vs complete
    const int k0 = b * TT + kt * 64;
#pragma unroll
    for (int i = tid; i < 64 * 16; i += 64) {
      int r = i >> 4, c4 = i & 15;
      const float4 kv = *(const float4*)(K + (size_t)(k0 + r) * DD + h0 + c4 * 4);
      KP[c4 * 4 + 0][r] = kv.x; KP[c4 * 4 + 1][r] = kv.y;
      KP[c4 * 4 + 2][r] = kv.z; KP[c4 * 4 + 3][r] = kv.w;
      const float4 vv = *(const float4*)(V + (size_t)(k0 + r) * DD + h0 + c4 * 4);
      *(float4*)&Vs[r][c4 * 4] = vv;
    }
    __syncthreads();
    // S = Q K^T  (8q x 8k per thread)
    float s[8][8];
#pragma unroll
    for (int i = 0; i < 8; ++i)
#pragma unroll
      for (int j = 0; j < 8; ++j) s[i][j] = 0.0f;
    for (int d = 0; d < DH; ++d) {
      const float4 qa = *(const float4*)&Qst[d][ty * 8];
      const float4 qb = *(const float4*)&Qst[d][ty * 8 + 4];
      const float4 ka = *(const float4*)&KP[d][tx * 8];
      const float4 kb = *(const float4*)&KP[d][tx * 8 + 4];
      const float qv[8] = {qa.x, qa.y, qa.z, qa.w, qb.x, qb.y, qb.z, qb.w};
      const float kv[8] = {ka.x, ka.y, ka.z, ka.w, kb.x, kb.y, kb.z, kb.w};
#pragma unroll
      for (int ii = 0; ii < 8; ++ii)
#pragma unroll
        for (int jj = 0; jj < 8; ++jj)
          s[ii][jj] = fmaf(qv[ii], kv[jj], s[ii][jj]);
    }
    // online softmax per q-row (rows shared by 8 consecutive lanes: tx group)
#pragma unroll
    for (int ii = 0; ii < 8; ++ii) {
      float mx = -INFINITY;
#pragma unroll
      for (int jj = 0; jj < 8; ++jj) {
        s[ii][jj] *= 0.125f;                 // dh^-0.5
        mx = fmaxf(mx, s[ii][jj]);
      }
      mx = fmaxf(mx, __shfl_xor(mx, 1));
      mx = fmaxf(mx, __shfl_xor(mx, 2));
      mx = fmaxf(mx, __shfl_xor(mx, 4));
      const float mn = fmaxf(m[ii], mx);
      const float al = expf(m[ii] - mn);     // 0 on first tile
      float rs = 0.0f;
#pragma unroll
      for (int jj = 0; jj < 8; ++jj) {
        const float p = expf(s[ii][jj] - mn);
        s[ii][jj] = p; rs += p;
      }
      rs += __shfl_xor(rs, 1);
      rs += __shfl_xor(rs, 2);
      rs += __shfl_xor(rs, 4);
      l[ii] = l[ii] * al + rs;
      m[ii] = mn;
#pragma unroll
      for (int jj = 0; jj < 8; ++jj) acc[ii][jj] *= al;
    }
    __syncthreads();   // all S-phase reads of KP done
    // write P transposed: KP[k][q]
#pragma unroll
    for (int ii = 0; ii < 8; ++ii)
#pragma unroll
      for (int jj = 0; jj < 8; ++jj)
        KP[tx * 8 + jj][ty * 8 + ii] = s[ii][jj];
    __syncthreads();
    // O += P V   (8q x 8d per thread)
    for (int k = 0; k < 64; ++k) {
      const float4 pa = *(const float4*)&KP[k][ty * 8];
      const float4 pb = *(const float4*)&KP[k][ty * 8 + 4];
      const float4 va = *(const float4*)&Vs[k][tx * 8];
      const float4 vb = *(const float4*)&Vs[k][tx * 8 + 4];
      const float pv[8] = {pa.x, pa.y, pa.z, pa.w, pb.x, pb.y, pb.z, pb.w};
      const float vv[8] = {va.x, va.y, va.z, va.w, vb.x, vb.y, vb.z, vb.w};
#pragma unroll
      for (int ii = 0; ii < 8; ++ii)
#pragma unroll
        for (int jj = 0; jj < 8; ++jj)
          acc[ii][jj] = fmaf(pv[ii], vv[jj], acc[ii][jj]);
    }
  }
  // normalize + store
#pragma unroll
  for (int ii = 0; ii < 8; ++ii) {
    const float inv = 1.0f / l[ii];
    float o[8];
#pragma unroll
    for (int jj = 0; jj < 8; ++jj) o[jj] = acc[ii][jj] * inv;
    float* dst = O + (size_t)(n0 + ty * 8 + ii) * DD + h0 + tx * 8;
    *(float4*)dst       = *(float4*)&o[0];
    *(float4*)(dst + 4) = *(float4*)&o[4];
  }
}

// ---------------- top-k running update over one slot tile ----------------
// S: [NT, STILE] scores for slots s0..s0+STILE-1. State sv/si: [NT,8].
__global__ __launch_bounds__(64) void topk_update(const float* __restrict__ S, int s0, int first,
                                                  float* __restrict__ sv, int* __restrict__ si) {
  const int n = blockIdx.x;
  const int lane = threadIdx.x;
  const float* row = S + (size_t)n * STILE;
  float lv[TOPK]; int li[TOPK];
#pragma unroll
  for (int i = 0; i < TOPK; ++i) { lv[i] = -INFINITY; li[i] = -1; }
  float vmin = -INFINITY; int imin = 0;
  for (int c = lane; c < STILE; c += 64) {
    const float v = row[c];
    if (v > vmin) {
      lv[imin] = v; li[imin] = s0 + c;
      vmin = lv[0]; imin = 0;
#pragma unroll
      for (int i = 1; i < TOPK; ++i)
        if (lv[i] < vmin) { vmin = lv[i]; imin = i; }
    }
  }
  __shared__ float cv[64 * TOPK + TOPK];
  __shared__ int   ci[64 * TOPK + TOPK];
#pragma unroll
  for (int i = 0; i < TOPK; ++i) { cv[lane * TOPK + i] = lv[i]; ci[lane * TOPK + i] = li[i]; }
  if (lane < TOPK) {
    cv[512 + lane] = first ? -INFINITY : sv[(size_t)n * TOPK + lane];
    ci[512 + lane] = first ? -1        : si[(size_t)n * TOPK + lane];
  }
  __syncthreads();
  for (int r = 0; r < TOPK; ++r) {
    float bmv = -INFINITY; int bp = lane;
    for (int c = lane; c < 520; c += 64) {
      if (cv[c] > bmv) { bmv = cv[c]; bp = c; }
    }
#pragma unroll
    for (int off = 32; off > 0; off >>= 1) {
      const float ov = __shfl_xor(bmv, off);
      const int   op = __shfl_xor(bp, off);
      if (ov > bmv || (ov == bmv && op < bp)) { bmv = ov; bp = op; }
    }
    __syncthreads();
    if (lane == 0) {
      sv[(size_t)n * TOPK + r] = bmv;
      si[(size_t)n * TOPK + r] = ci[bp];
      cv[bp] = -INFINITY;
    }
    __syncthreads();
  }
}

// ---------------- weighted memory read: out[n] = sum_k softmax(sv)_k * memV[si_k] ----------------
__global__ __launch_bounds__(64) void mem_read_k(const float* __restrict__ sv, const int* __restrict__ si,
                                                 const float* __restrict__ memV, float* __restrict__ out) {
  const int n = blockIdx.x;
  const int lane = threadIdx.x;
  float w[TOPK]; int id[TOPK];
  float mx = -INFINITY;
#pragma unroll
  for (int i = 0; i < TOPK; ++i) {
    w[i] = sv[(size_t)n * TOPK + i];
    id[i] = si[(size_t)n * TOPK + i];
    mx = fmaxf(mx, w[i]);
  }
  float s = 0.0f;
#pragma unroll
  for (int i = 0; i < TOPK; ++i) { w[i] = expf(w[i] - mx); s += w[i]; }
  const float inv = 1.0f / s;
  float o[8] = {0, 0, 0, 0, 0, 0, 0, 0};
#pragma unroll
  for (int i = 0; i < TOPK; ++i) {
    const float wi = w[i] * inv;
    const float* vr = memV + (size_t)id[i] * DD + lane * 8;
    const float4 a = *(const float4*)vr;
    const float4 b = *(const float4*)(vr + 4);
    o[0] += wi * a.x; o[1] += wi * a.y; o[2] += wi * a.z; o[3] += wi * a.w;
    o[4] += wi * b.x; o[5] += wi * b.y; o[6] += wi * b.z; o[7] += wi * b.w;
  }
  float* dst = out + (size_t)n * DD + lane * 8;
  *(float4*)dst       = *(float4*)&o[0];
  *(float4*)(dst + 4) = *(float4*)&o[4];
}

extern "C" void kernel_launch(void* const* d_in, const int* in_sizes, int n_in,
                              void* d_out, int out_size, void* d_ws, size_t ws_size,
                              hipStream_t stream) {
  const int*   input_ids = (const int*)d_in[0];
  const float* tok_embed = (const float*)d_in[1];
  const float* pos_embed = (const float*)d_in[2];
  const float* blk_wq    = (const float*)d_in[3];
  const float* blk_wk    = (const float*)d_in[4];
  const float* blk_wv    = (const float*)d_in[5];
  const float* blk_wo    = (const float*)d_in[6];
  const float* blk_bo    = (const float*)d_in[7];
  const float* blk_norm1 = (const float*)d_in[8];
  const float* blk_ffw1  = (const float*)d_in[9];
  const float* blk_ffb1  = (const float*)d_in[10];
  const float* blk_ffw2  = (const float*)d_in[11];
  const float* blk_ffb2  = (const float*)d_in[12];
  const float* blk_norm2 = (const float*)d_in[13];
  const float* mem_K     = (const float*)d_in[14];
  const float* mem_V     = (const float*)d_in[15];
  const float* salience  = (const float*)d_in[16];
  const float* wq_mem    = (const float*)d_in[17];
  const float* bq_mem    = (const float*)d_in[18];
  const float* w_read    = (const float*)d_in[19];
  const float* b_read    = (const float*)d_in[20];
  const float* norm_out_w= (const float*)d_in[21];
  float* out = (float*)d_out;

  float* x    = (float*)d_ws;                 // NT*DD
  float* q    = x    + (size_t)NT * DD;       // NT*DD (also mq)
  float* kbuf = q    + (size_t)NT * DD;       // NT*DD
  float* vbuf = kbuf + (size_t)NT * DD;       // NT*DD
  float* ao   = vbuf + (size_t)NT * DD;       // NT*DD (also mem read result)
  float* h    = ao   + (size_t)NT * DD;       // NT*FFD (FFN mid / score tiles)
  float* sv   = h    + (size_t)NT * FFD;      // NT*8
  int*   si   = (int*)(sv + (size_t)NT * TOPK);

  const float inv_sqrt_d = 0.044194173824159216f;  // 512^-0.5

  embed_k<<<NT, 128, 0, stream>>>(input_ids, tok_embed, pos_embed, x);

  const dim3 gDD(DD / GBN, NT / GBM);      // (4, 32)
  const dim3 gFF(FFD / GBN, NT / GBM);     // (16, 32)

  for (int l = 0; l < 4; ++l) {
    const float* wq = blk_wq + (size_t)l * DD * DD;
    const float* wk = blk_wk + (size_t)l * DD * DD;
    const float* wv = blk_wv + (size_t)l * DD * DD;
    const float* wo = blk_wo + (size_t)l * DD * DD;
    const float* bo = blk_bo + (size_t)l * DD;
    const float* n1 = blk_norm1 + (size_t)l * DD;
    const float* w1 = blk_ffw1 + (size_t)l * DD * FFD;
    const float* b1 = blk_ffb1 + (size_t)l * FFD;
    const float* w2 = blk_ffw2 + (size_t)l * FFD * DD;
    const float* b2 = blk_ffb2 + (size_t)l * DD;
    const float* n2 = blk_norm2 + (size_t)l * DD;

    gemm_k<<<gDD, 256, 0, stream>>>(x, wq, nullptr, nullptr, q,    NT, DD, DD, 1.0f, 0, 0);
    gemm_k<<<gDD, 256, 0, stream>>>(x, wk, nullptr, nullptr, kbuf, NT, DD, DD, 1.0f, 0, 0);
    gemm_k<<<gDD, 256, 0, stream>>>(x, wv, nullptr, nullptr, vbuf, NT, DD, DD, 1.0f, 0, 0);
    attn_k<<<dim3(TT / 64, HH, 2), 64, 0, stream>>>(q, kbuf, vbuf, ao);
    gemm_k<<<gDD, 256, 0, stream>>>(ao, wo, bo, x, x, NT, DD, DD, 1.0f, 0, 0);
    rms_k<<<NT, 128, 0, stream>>>(x, n1);
    gemm_k<<<gFF, 256, 0, stream>>>(x, w1, b1, nullptr, h, NT, FFD, DD, 1.0f, 1, 0);
    gemm_k<<<gDD, 256, 0, stream>>>(h, w2, b2, x, x, NT, DD, FFD, 1.0f, 0, 0);
    rms_k<<<NT, 128, 0, stream>>>(x, n2);
  }

  // memory query projection: mq (into q buffer)
  gemm_k<<<gDD, 256, 0, stream>>>(x, wq_mem, bq_mem, nullptr, q, NT, DD, DD, 1.0f, 0, 0);

  // slot scoring + running top-k over 16 tiles of 2048 slots
  for (int st = 0; st < NSLOT / STILE; ++st) {
    gemm_k<<<gFF, 256, 0, stream>>>(q, mem_K + (size_t)st * STILE * DD,
                                    salience + (size_t)st * STILE, nullptr, h,
                                    NT, STILE, DD, inv_sqrt_d, 0, 1);
    topk_update<<<NT, 64, 0, stream>>>(h, st * STILE, st == 0 ? 1 : 0, sv, si);
  }

  mem_read_k<<<NT, 64, 0, stream>>>(sv, si, mem_V, ao);
  gemm_k<<<gDD, 256, 0, stream>>>(ao, w_read, b_read, x, x, NT, DD, DD, 1.0f, 0, 0);
  rms_k<<<NT, 128, 0, stream>>>(x, norm_out_w);

  // tied LM head: logits = x @ tok_embed^T
  gemm_k<<<dim3(32000 / GBN, NT / GBM), 256, 0, stream>>>(x, tok_embed, nullptr, nullptr, out,
                                                          NT, 32000, DD, 1.0f, 0, 1);
}